// Round 6
// baseline (324.758 us; speedup 1.0000x reference)
//
#include <hip/hip_runtime.h>
#include <hip/hip_bf16.h>
#include <cstdint>
#include <cstddef>

#define T_TOK 2048
#define HDIM  1024
#define FDIM  2048
#define NEXP  8
#define BM    128

typedef __attribute__((ext_vector_type(8))) short bf16x8;
typedef __attribute__((ext_vector_type(4))) float f32x4;

__device__ __forceinline__ unsigned short f2b(float f) {
  __hip_bfloat16 h = __float2bfloat16(f);
  return __builtin_bit_cast(unsigned short, h);
}

__device__ __forceinline__ void gload16(const void* g, void* l) {
  __builtin_amdgcn_global_load_lds(
      (const __attribute__((address_space(1))) unsigned int*)g,
      (__attribute__((address_space(3))) unsigned int*)l, 16, 0, 0);
}

// two f32x4 (from LDS half-chunks) -> bf16x8 fragment (v_cvt_pk_bf16_f32 x4)
__device__ __forceinline__ bf16x8 cvt_frag(f32x4 lo, f32x4 hi) {
  union { unsigned short u[8]; bf16x8 v; } r;
  r.u[0] = f2b(lo[0]); r.u[1] = f2b(lo[1]); r.u[2] = f2b(lo[2]); r.u[3] = f2b(lo[3]);
  r.u[4] = f2b(hi[0]); r.u[5] = f2b(hi[1]); r.u[6] = f2b(hi[2]); r.u[7] = f2b(hi[3]);
  return r.v;
}

// ---------------- router + sparsemixer (eval) + x->bf16 ----------------
__global__ __launch_bounds__(256) void router_k(
    const float* __restrict__ x, const float* __restrict__ rw,
    float* __restrict__ wslot, int* __restrict__ rows,
    int* __restrict__ cnt, unsigned short* __restrict__ xb)
{
  const int wave = threadIdx.x >> 6, lane = threadIdx.x & 63;
  const int t = blockIdx.x * 4 + wave;
  const float* xr = x + (size_t)t * HDIM;
  unsigned short* xbr = xb + (size_t)t * HDIM;
  float acc[NEXP];
#pragma unroll
  for (int e = 0; e < NEXP; ++e) acc[e] = 0.f;
  for (int i = 0; i < HDIM / 64; ++i) {
    const int h = i * 64 + lane;
    const float xv = xr[h];
    xbr[h] = f2b(xv);
#pragma unroll
    for (int e = 0; e < NEXP; ++e) acc[e] += xv * rw[e * HDIM + h];
  }
#pragma unroll
  for (int e = 0; e < NEXP; ++e) {
#pragma unroll
    for (int off = 32; off; off >>= 1) acc[e] += __shfl_xor(acc[e], off);
  }
  if (lane == 0) {
    float m1 = acc[0]; int i1 = 0;
#pragma unroll
    for (int e = 1; e < NEXP; ++e) if (acc[e] > m1) { m1 = acc[e]; i1 = e; }
    float sum1 = 0.f;
#pragma unroll
    for (int e = 0; e < NEXP; ++e) {
      const float f = fmaxf(fabsf(acc[e]), m1);
      if (m1 - acc[e] <= 0.02f * f) sum1 += expf(acc[e] - m1);
    }
    float m2 = -3.4e38f; int i2 = 0;
#pragma unroll
    for (int e = 0; e < NEXP; ++e)
      if (e != i1 && acc[e] > m2) { m2 = acc[e]; i2 = e; }
    float sum2 = 0.f;
#pragma unroll
    for (int e = 0; e < NEXP; ++e) {
      if (e == i1) continue;
      const float f = fmaxf(fabsf(acc[e]), m2);
      if (m2 - acc[e] <= 0.02f * f) sum2 += expf(acc[e] - m2);
    }
    wslot[2 * t]     = 1.f / sum1;
    wslot[2 * t + 1] = 1.f / sum2;
    int p1 = atomicAdd(&cnt[i1], 1); rows[i1 * T_TOK + p1] = 2 * t;
    int p2 = atomicAdd(&cnt[i2], 1); rows[i2 * T_TOK + p2] = 2 * t + 1;
  }
}

// ---------------- gate/up GEMM: A bf16 (gathered) + B fp32 direct ----------------
// A chunk c=wr*4+mf: 512 bf16, lane-linear 16B.
// B chunk c=wc*2+nf: 512 fp32 as two half-chunks of 256 fp32 (lane*16B each).
__global__ __launch_bounds__(256) void gemm_gateup_k(
    const unsigned short* __restrict__ xb,
    const float* __restrict__ wg32, const float* __restrict__ wu32,
    const int* __restrict__ rows, const int* __restrict__ cnt,
    const float* __restrict__ wslot, unsigned short* __restrict__ hbuf)
{
  const int bx = blockIdx.x;
  const int e  = bx >> 9;
  const int rm = bx & 511;
  const int mt = rm >> 5;
  const int nt = rm & 31;
  const int cnt_e = cnt[e];
  if (mt * BM >= cnt_e) return;

  __shared__ unsigned short As[2][4096];   // 8 chunks x 512 bf16
  __shared__ float Bg[2][2048];            // 4 chunks x (2 x 256 fp32)
  __shared__ float Bu[2][2048];
  __shared__ int ldsRow[BM];

  const int tid = threadIdx.x;
  if (tid < BM) {
    const int idx = mt * BM + tid;
    ldsRow[tid] = (idx < cnt_e) ? rows[e * T_TOK + idx] : -1;
  }
  __syncthreads();

  const int lane = tid & 63, w = tid >> 6;
  const int wr = w >> 1, wc = w & 1;
  const int lr = lane & 15, lq = lane >> 4;

  // A staging: chunks c = it*4+w
  const unsigned short* aS[2];
  int aOff[2];
#pragma unroll
  for (int it = 0; it < 2; ++it) {
    const int c = it * 4 + w;
    const int row = (c >> 2) * 64 + (c & 3) * 16 + lr;
    int r = ldsRow[row]; if (r < 0) r = 0;
    aS[it] = xb + (size_t)(r >> 1) * HDIM + lq * 8;
    aOff[it] = c * 512 + lane * 8;
  }
  // B staging: chunk c = w; lane's 8 floats split across half0/half1
  const int rowB = (w >> 1) * 32 + (w & 1) * 16 + lr;
  const float* gS = wg32 + ((size_t)e * FDIM + nt * 64 + rowB) * HDIM + lq * 8;
  const float* uS = wu32 + ((size_t)e * FDIM + nt * 64 + rowB) * HDIM + lq * 8;
  const int bOff0 = w * 512 + lane * 4;         // half0: floats 0..3
  const int bOff1 = w * 512 + 256 + lane * 4;   // half1: floats 4..7

  f32x4 accg[4][2], accu[4][2];
#pragma unroll
  for (int mf = 0; mf < 4; ++mf)
#pragma unroll
    for (int nf = 0; nf < 2; ++nf) {
      accg[mf][nf] = (f32x4){0.f, 0.f, 0.f, 0.f};
      accu[mf][nf] = (f32x4){0.f, 0.f, 0.f, 0.f};
    }

  // prologue
  gload16(aS[0], &As[0][aOff[0]]);
  gload16(aS[1], &As[0][aOff[1]]);
  gload16(gS,     &Bg[0][bOff0]);
  gload16(gS + 4, &Bg[0][bOff1]);
  gload16(uS,     &Bu[0][bOff0]);
  gload16(uS + 4, &Bu[0][bOff1]);
  __syncthreads();

  int cur = 0;
  for (int k = 0; k < 32; ++k) {
    const int nxt = cur ^ 1;
    if (k + 1 < 32) {
      const int ko = (k + 1) * 32;
      gload16(aS[0] + ko, &As[nxt][aOff[0]]);
      gload16(aS[1] + ko, &As[nxt][aOff[1]]);
      gload16(gS + ko,     &Bg[nxt][bOff0]);
      gload16(gS + ko + 4, &Bg[nxt][bOff1]);
      gload16(uS + ko,     &Bu[nxt][bOff0]);
      gload16(uS + ko + 4, &Bu[nxt][bOff1]);
    }
    bf16x8 a[4], bg[2], bu[2];
#pragma unroll
    for (int mf = 0; mf < 4; ++mf)
      a[mf] = *(const bf16x8*)&As[cur][(wr * 4 + mf) * 512 + lane * 8];
#pragma unroll
    for (int nf = 0; nf < 2; ++nf) {
      const int c = wc * 2 + nf;
      bg[nf] = cvt_frag(*(const f32x4*)&Bg[cur][c * 512 + lane * 4],
                        *(const f32x4*)&Bg[cur][c * 512 + 256 + lane * 4]);
      bu[nf] = cvt_frag(*(const f32x4*)&Bu[cur][c * 512 + lane * 4],
                        *(const f32x4*)&Bu[cur][c * 512 + 256 + lane * 4]);
    }
#pragma unroll
    for (int mf = 0; mf < 4; ++mf)
#pragma unroll
      for (int nf = 0; nf < 2; ++nf) {
        accg[mf][nf] = __builtin_amdgcn_mfma_f32_16x16x32_bf16(a[mf], bg[nf], accg[mf][nf], 0, 0, 0);
        accu[mf][nf] = __builtin_amdgcn_mfma_f32_16x16x32_bf16(a[mf], bu[nf], accu[mf][nf], 0, 0, 0);
      }
    __syncthreads();
    cur = nxt;
  }

  // epilogue: h = silu(g)*u*w   (C/D: col=lane&15, row=(lane>>4)*4+i)
#pragma unroll
  for (int mf = 0; mf < 4; ++mf)
#pragma unroll
    for (int nf = 0; nf < 2; ++nf) {
      const int col = nt * 64 + wc * 32 + nf * 16 + lr;
#pragma unroll
      for (int i = 0; i < 4; ++i) {
        const int lrow = wr * 64 + mf * 16 + lq * 4 + i;
        const int r = ldsRow[lrow];
        if (r < 0) continue;
        const float g = accg[mf][nf][i], u = accu[mf][nf][i];
        const float val = g / (1.f + __expf(-g)) * u * wslot[r];
        hbuf[(size_t)r * FDIM + col] = f2b(val);
      }
    }
}

// ---------------- down GEMM: A bf16 (hbuf) + B fp32 direct, plain stores ----------------
__global__ __launch_bounds__(256) void gemm_down_k(
    const unsigned short* __restrict__ hbuf,
    const float* __restrict__ wd32,
    const int* __restrict__ rows, const int* __restrict__ cnt,
    float* __restrict__ obuf)
{
  const int bx = blockIdx.x;
  const int e  = bx >> 8;
  const int rm = bx & 255;
  const int mt = rm >> 4;
  const int nt = rm & 15;
  const int cnt_e = cnt[e];
  if (mt * BM >= cnt_e) return;

  __shared__ unsigned short As[2][4096];   // 8 chunks x 512 bf16
  __shared__ float Bs[2][2048];            // 4 chunks x (2 x 256 fp32)
  __shared__ int ldsRow[BM];

  const int tid = threadIdx.x;
  if (tid < BM) {
    const int idx = mt * BM + tid;
    ldsRow[tid] = (idx < cnt_e) ? rows[e * T_TOK + idx] : -1;
  }
  __syncthreads();

  const int lane = tid & 63, w = tid >> 6;
  const int wr = w >> 1, wc = w & 1;
  const int lr = lane & 15, lq = lane >> 4;

  const unsigned short* aS[2];
  int aOff[2];
#pragma unroll
  for (int it = 0; it < 2; ++it) {
    const int c = it * 4 + w;
    const int row = (c >> 2) * 64 + (c & 3) * 16 + lr;
    int r = ldsRow[row]; if (r < 0) r = 0;
    aS[it] = hbuf + (size_t)r * FDIM + lq * 8;
    aOff[it] = c * 512 + lane * 8;
  }
  const int rowB = (w >> 1) * 32 + (w & 1) * 16 + lr;
  const float* dS = wd32 + ((size_t)e * HDIM + nt * 64 + rowB) * FDIM + lq * 8;
  const int bOff0 = w * 512 + lane * 4;
  const int bOff1 = w * 512 + 256 + lane * 4;

  f32x4 acc[4][2];
#pragma unroll
  for (int mf = 0; mf < 4; ++mf)
#pragma unroll
    for (int nf = 0; nf < 2; ++nf) acc[mf][nf] = (f32x4){0.f, 0.f, 0.f, 0.f};

  gload16(aS[0], &As[0][aOff[0]]);
  gload16(aS[1], &As[0][aOff[1]]);
  gload16(dS,     &Bs[0][bOff0]);
  gload16(dS + 4, &Bs[0][bOff1]);
  __syncthreads();

  int cur = 0;
  for (int k = 0; k < 64; ++k) {     // K = 2048 / 32
    const int nxt = cur ^ 1;
    if (k + 1 < 64) {
      const int ko = (k + 1) * 32;
      gload16(aS[0] + ko, &As[nxt][aOff[0]]);
      gload16(aS[1] + ko, &As[nxt][aOff[1]]);
      gload16(dS + ko,     &Bs[nxt][bOff0]);
      gload16(dS + ko + 4, &Bs[nxt][bOff1]);
    }
    bf16x8 a[4], b[2];
#pragma unroll
    for (int mf = 0; mf < 4; ++mf)
      a[mf] = *(const bf16x8*)&As[cur][(wr * 4 + mf) * 512 + lane * 8];
#pragma unroll
    for (int nf = 0; nf < 2; ++nf) {
      const int c = wc * 2 + nf;
      b[nf] = cvt_frag(*(const f32x4*)&Bs[cur][c * 512 + lane * 4],
                       *(const f32x4*)&Bs[cur][c * 512 + 256 + lane * 4]);
    }
#pragma unroll
    for (int mf = 0; mf < 4; ++mf)
#pragma unroll
      for (int nf = 0; nf < 2; ++nf)
        acc[mf][nf] = __builtin_amdgcn_mfma_f32_16x16x32_bf16(a[mf], b[nf], acc[mf][nf], 0, 0, 0);
    __syncthreads();
    cur = nxt;
  }

#pragma unroll
  for (int mf = 0; mf < 4; ++mf)
#pragma unroll
    for (int nf = 0; nf < 2; ++nf) {
      const int col = nt * 64 + wc * 32 + nf * 16 + lr;
#pragma unroll
      for (int i = 0; i < 4; ++i) {
        const int lrow = wr * 64 + mf * 16 + lq * 4 + i;
        const int r = ldsRow[lrow];
        if (r < 0) continue;
        obuf[(size_t)r * HDIM + col] = acc[mf][nf][i];
      }
    }
}

// ---------------- combine: out[t] = obuf[2t] + obuf[2t+1] ----------------
__global__ __launch_bounds__(256) void combine_k(const float* __restrict__ obuf,
                                                 float* __restrict__ out)
{
  const int i = blockIdx.x * 256 + threadIdx.x;
  const int t = i >> 8, c = i & 255;
  const float4* o4 = (const float4*)obuf;
  const float4 a = o4[(size_t)(2 * t) * (HDIM / 4) + c];
  const float4 b = o4[(size_t)(2 * t + 1) * (HDIM / 4) + c];
  float4 r; r.x = a.x + b.x; r.y = a.y + b.y; r.z = a.z + b.z; r.w = a.w + b.w;
  ((float4*)out)[i] = r;
}

extern "C" void kernel_launch(void* const* d_in, const int* in_sizes, int n_in,
                              void* d_out, int out_size, void* d_ws, size_t ws_size,
                              hipStream_t stream) {
  const float* x  = (const float*)d_in[0];
  const float* rw = (const float*)d_in[1];
  const float* wg = (const float*)d_in[2];
  const float* wu = (const float*)d_in[3];
  const float* wd = (const float*)d_in[4];
  float* out = (float*)d_out;

  char* ws = (char*)d_ws;
  unsigned short* hbuf = (unsigned short*)ws;                        // 16 MiB
  unsigned short* xb   = (unsigned short*)(ws + (16u << 20));        // 4 MiB
  int*   cnt   = (int*)  (ws + (20u << 20));                         // 256 B
  int*   rows  = (int*)  (ws + (20u << 20) + 256);                   // 64 KiB
  float* wslot = (float*)(ws + (20u << 20) + 256 + 65536);           // 16 KiB
  float* obuf  = (float*)(ws + (24ull << 20));                       // 16 MiB

  hipMemsetAsync(cnt, 0, 256, stream);
  router_k<<<T_TOK / 4, 256, 0, stream>>>(x, rw, wslot, rows, cnt, xb);
  gemm_gateup_k<<<NEXP * 16 * 32, 256, 0, stream>>>(xb, wg, wu, rows, cnt, wslot, hbuf);
  gemm_down_k<<<NEXP * 16 * 16, 256, 0, stream>>>(hbuf, wd, rows, cnt, obuf);
  combine_k<<<T_TOK * HDIM / 4 / 256, 256, 0, stream>>>(obuf, out);
}

// Round 7
// 293.652 us; speedup vs baseline: 1.1059x; 1.1059x over previous
//
#include <hip/hip_runtime.h>
#include <hip/hip_bf16.h>
#include <cstdint>
#include <cstddef>

#define T_TOK 2048
#define HDIM  1024
#define FDIM  2048
#define NEXP  8
#define BM    128

typedef __attribute__((ext_vector_type(8))) short bf16x8;
typedef __attribute__((ext_vector_type(4))) float f32x4;

__device__ __forceinline__ unsigned short f2b(float f) {
  __hip_bfloat16 h = __float2bfloat16(f);
  return __builtin_bit_cast(unsigned short, h);
}

__device__ __forceinline__ void gload16(const void* g, void* l) {
  __builtin_amdgcn_global_load_lds(
      (const __attribute__((address_space(1))) unsigned int*)g,
      (__attribute__((address_space(3))) unsigned int*)l, 16, 0, 0);
}

__device__ __forceinline__ void cvt8(const float* __restrict__ s,
                                     unsigned short* __restrict__ d, int i) {
  const float4 f0 = ((const float4*)s)[2 * i];
  const float4 f1 = ((const float4*)s)[2 * i + 1];
  union { unsigned short u[8]; uint4 v; } p;
  p.u[0] = f2b(f0.x); p.u[1] = f2b(f0.y); p.u[2] = f2b(f0.z); p.u[3] = f2b(f0.w);
  p.u[4] = f2b(f1.x); p.u[5] = f2b(f1.y); p.u[6] = f2b(f1.z); p.u[7] = f2b(f1.w);
  ((uint4*)d)[i] = p.v;
}

// ---------------- router (256 blocks) + wg/wu conversion (512 blocks) ----------------
__global__ __launch_bounds__(512) void router_conv_k(
    const float* __restrict__ x, const float* __restrict__ rw,
    float* __restrict__ wslot, int* __restrict__ rows,
    int* __restrict__ cnt, unsigned short* __restrict__ xb,
    const float* __restrict__ wg32, const float* __restrict__ wu32,
    unsigned short* __restrict__ wg16, unsigned short* __restrict__ wu16)
{
  const int bx = blockIdx.x;
  if (bx >= 256) {
    const int b2 = bx - 256;
    const float* s = (b2 < 256) ? wg32 : wu32;
    unsigned short* d = (b2 < 256) ? wg16 : wu16;
    const int base = (b2 & 255) * 512 + threadIdx.x;   // 131072 threads
#pragma unroll
    for (int it = 0; it < 16; ++it) cvt8(s, d, base + it * 131072);
    return;
  }
  const int wave = threadIdx.x >> 6, lane = threadIdx.x & 63;
  const int t = bx * 8 + wave;
  const float* xr = x + (size_t)t * HDIM;
  unsigned short* xbr = xb + (size_t)t * HDIM;
  float acc[NEXP];
#pragma unroll
  for (int e = 0; e < NEXP; ++e) acc[e] = 0.f;
  for (int i = 0; i < HDIM / 64; ++i) {
    const int h = i * 64 + lane;
    const float xv = xr[h];
    xbr[h] = f2b(xv);
#pragma unroll
    for (int e = 0; e < NEXP; ++e) acc[e] += xv * rw[e * HDIM + h];
  }
#pragma unroll
  for (int e = 0; e < NEXP; ++e) {
#pragma unroll
    for (int off = 32; off; off >>= 1) acc[e] += __shfl_xor(acc[e], off);
  }
  if (lane == 0) {
    float m1 = acc[0]; int i1 = 0;
#pragma unroll
    for (int e = 1; e < NEXP; ++e) if (acc[e] > m1) { m1 = acc[e]; i1 = e; }
    float sum1 = 0.f;
#pragma unroll
    for (int e = 0; e < NEXP; ++e) {
      const float f = fmaxf(fabsf(acc[e]), m1);
      if (m1 - acc[e] <= 0.02f * f) sum1 += expf(acc[e] - m1);
    }
    float m2 = -3.4e38f; int i2 = 0;
#pragma unroll
    for (int e = 0; e < NEXP; ++e)
      if (e != i1 && acc[e] > m2) { m2 = acc[e]; i2 = e; }
    float sum2 = 0.f;
#pragma unroll
    for (int e = 0; e < NEXP; ++e) {
      if (e == i1) continue;
      const float f = fmaxf(fabsf(acc[e]), m2);
      if (m2 - acc[e] <= 0.02f * f) sum2 += expf(acc[e] - m2);
    }
    wslot[2 * t]     = 1.f / sum1;
    wslot[2 * t + 1] = 1.f / sum2;
    int p1 = atomicAdd(&cnt[i1], 1); rows[i1 * T_TOK + p1] = 2 * t;
    int p2 = atomicAdd(&cnt[i2], 1); rows[i2 * T_TOK + p2] = 2 * t + 1;
  }
}

// ---------------- gate/up GEMM: 128x128x32, all-bf16 gload16, + leading wd conv ----
// frag-major LDS: chunk = 512 bf16 (16 rows x 32 k), lane-linear 16B.
// A chunks 0..7 (c = wr*4+mf), Bg/Bu chunks 0..7 (c = wc*2+nf). 8 waves, each stages chunk w.
__global__ __launch_bounds__(512) void gemm_gateup_k(
    const unsigned short* __restrict__ xb,
    const unsigned short* __restrict__ wg16, const unsigned short* __restrict__ wu16,
    const int* __restrict__ rows, const int* __restrict__ cnt,
    const float* __restrict__ wslot, unsigned short* __restrict__ hbuf,
    const float* __restrict__ wd32, unsigned short* __restrict__ wd16)
{
  const int bx = blockIdx.x;
  if (bx < 256) {   // leading blocks: wd fp32->bf16 (overlaps with GEMM blocks)
    const int base = bx * 512 + threadIdx.x;
#pragma unroll
    for (int it = 0; it < 16; ++it) cvt8(wd32, wd16, base + it * 131072);
    return;
  }
  const int bxx = bx - 256;
  const int e  = bxx >> 8;          // 16 mt x 16 nt = 256
  const int mt = (bxx >> 4) & 15;
  const int nt = bxx & 15;
  const int cnt_e = cnt[e];
  if (mt * BM >= cnt_e) return;

  __shared__ unsigned short As[4096];   // 8 chunks x 512
  __shared__ unsigned short Bg[4096];
  __shared__ unsigned short Bu[4096];
  __shared__ int ldsRow[BM];

  const int tid = threadIdx.x;
  if (tid < BM) {
    const int idx = mt * BM + tid;
    ldsRow[tid] = (idx < cnt_e) ? rows[e * T_TOK + idx] : -1;
  }
  __syncthreads();

  const int lane = tid & 63, w = tid >> 6;
  const int wr = w >> 2, wc = w & 3;    // 2x4 wave grid: 64 rows x 32 cols per wave
  const int lr = lane & 15, lq = lane >> 4;

  // staging: wave w stages chunk w of A, Bg, Bu (1 gload16 each per thread)
  int rA = ldsRow[w * 16 + lr]; if (rA < 0) rA = 0;
  const unsigned short* aS = xb + (size_t)(rA >> 1) * HDIM + lq * 8;
  const int browB = nt * 128 + w * 16 + lr;
  const unsigned short* gS = wg16 + ((size_t)e * FDIM + browB) * HDIM + lq * 8;
  const unsigned short* uS = wu16 + ((size_t)e * FDIM + browB) * HDIM + lq * 8;
  const int sOff = w * 512 + lane * 8;

  f32x4 accg[4][2], accu[4][2];
#pragma unroll
  for (int mf = 0; mf < 4; ++mf)
#pragma unroll
    for (int nf = 0; nf < 2; ++nf) {
      accg[mf][nf] = (f32x4){0.f, 0.f, 0.f, 0.f};
      accu[mf][nf] = (f32x4){0.f, 0.f, 0.f, 0.f};
    }

  for (int k = 0; k < 32; ++k) {        // K = 1024
    const int ko = k * 32;
    gload16(aS + ko, &As[sOff]);
    gload16(gS + ko, &Bg[sOff]);
    gload16(uS + ko, &Bu[sOff]);
    __syncthreads();                    // drain vmcnt: tile staged

    bf16x8 a[4], bg[2], bu[2];
#pragma unroll
    for (int mf = 0; mf < 4; ++mf)
      a[mf] = *(const bf16x8*)&As[(wr * 4 + mf) * 512 + lane * 8];
#pragma unroll
    for (int nf = 0; nf < 2; ++nf) {
      bg[nf] = *(const bf16x8*)&Bg[(wc * 2 + nf) * 512 + lane * 8];
      bu[nf] = *(const bf16x8*)&Bu[(wc * 2 + nf) * 512 + lane * 8];
    }
#pragma unroll
    for (int mf = 0; mf < 4; ++mf)
#pragma unroll
      for (int nf = 0; nf < 2; ++nf) {
        accg[mf][nf] = __builtin_amdgcn_mfma_f32_16x16x32_bf16(a[mf], bg[nf], accg[mf][nf], 0, 0, 0);
        accu[mf][nf] = __builtin_amdgcn_mfma_f32_16x16x32_bf16(a[mf], bu[nf], accu[mf][nf], 0, 0, 0);
      }
    __syncthreads();                    // protect LDS before restage
  }

  // epilogue: h = silu(g)*u*w   (C/D: col=lane&15, row=(lane>>4)*4+i)
#pragma unroll
  for (int mf = 0; mf < 4; ++mf)
#pragma unroll
    for (int nf = 0; nf < 2; ++nf) {
      const int col = nt * 128 + wc * 32 + nf * 16 + lr;
#pragma unroll
      for (int i = 0; i < 4; ++i) {
        const int lrow = wr * 64 + mf * 16 + lq * 4 + i;
        const int r = ldsRow[lrow];
        if (r < 0) continue;
        const float g = accg[mf][nf][i], u = accu[mf][nf][i];
        const float val = g / (1.f + __expf(-g)) * u * wslot[r];
        hbuf[(size_t)r * FDIM + col] = f2b(val);
      }
    }
}

// ---------------- down GEMM: 128x64x64, all-bf16 gload16, plain stores ----------------
// A: 16 chunks (c: rows (c>>1)*16, k-half (c&1)*32); B: 8 chunks (same split).
// Wave w stages A chunks {w, w+8} and B chunk w. 2x4 wave grid: 64 rows x 16 cols/wave.
__global__ __launch_bounds__(512) void gemm_down_k(
    const unsigned short* __restrict__ hbuf,
    const unsigned short* __restrict__ wd16,
    const int* __restrict__ rows, const int* __restrict__ cnt,
    float* __restrict__ obuf)
{
  const int bx = blockIdx.x;
  const int e  = bx >> 8;           // 16 mt x 16 nt
  const int mt = (bx >> 4) & 15;
  const int nt = bx & 15;
  const int cnt_e = cnt[e];
  if (mt * BM >= cnt_e) return;

  __shared__ unsigned short As[8192];   // 16 chunks x 512
  __shared__ unsigned short Bs[4096];   // 8 chunks x 512
  __shared__ int ldsRow[BM];

  const int tid = threadIdx.x;
  if (tid < BM) {
    const int idx = mt * BM + tid;
    ldsRow[tid] = (idx < cnt_e) ? rows[e * T_TOK + idx] : -1;
  }
  __syncthreads();

  const int lane = tid & 63, w = tid >> 6;
  const int wr = w >> 2, wc = w & 3;
  const int lr = lane & 15, lq = lane >> 4;

  // A staging: chunks c0 = w (rows 0..63), c1 = w+8 (rows 64..127); k-half (w&1)*32
  int r0 = ldsRow[(w >> 1) * 16 + lr];      if (r0 < 0) r0 = 0;
  int r1 = ldsRow[64 + (w >> 1) * 16 + lr]; if (r1 < 0) r1 = 0;
  const unsigned short* aS0 = hbuf + (size_t)r0 * FDIM + (w & 1) * 32 + lq * 8;
  const unsigned short* aS1 = hbuf + (size_t)r1 * FDIM + (w & 1) * 32 + lq * 8;
  const int aOff0 = w * 512 + lane * 8;
  const int aOff1 = (w + 8) * 512 + lane * 8;
  // B staging: chunk w: N-row (w>>1)*16+lr, k-half (w&1)*32
  const unsigned short* bS = wd16 +
      ((size_t)e * HDIM + nt * 64 + (w >> 1) * 16 + lr) * FDIM + (w & 1) * 32 + lq * 8;
  const int bOff = w * 512 + lane * 8;

  f32x4 acc[4];
#pragma unroll
  for (int mf = 0; mf < 4; ++mf) acc[mf] = (f32x4){0.f, 0.f, 0.f, 0.f};

  for (int k = 0; k < 32; ++k) {        // K = 2048, BK = 64
    const int ko = k * 64;
    gload16(aS0 + ko, &As[aOff0]);
    gload16(aS1 + ko, &As[aOff1]);
    gload16(bS + ko, &Bs[bOff]);
    __syncthreads();

    bf16x8 a[4][2], b[2];
#pragma unroll
    for (int ks = 0; ks < 2; ++ks) {
      b[ks] = *(const bf16x8*)&Bs[(wc * 2 + ks) * 512 + lane * 8];
#pragma unroll
      for (int mf = 0; mf < 4; ++mf)
        a[mf][ks] = *(const bf16x8*)&As[((wr * 4 + mf) * 2 + ks) * 512 + lane * 8];
    }
#pragma unroll
    for (int mf = 0; mf < 4; ++mf)
#pragma unroll
      for (int ks = 0; ks < 2; ++ks)
        acc[mf] = __builtin_amdgcn_mfma_f32_16x16x32_bf16(a[mf][ks], b[ks], acc[mf], 0, 0, 0);
    __syncthreads();
  }

#pragma unroll
  for (int mf = 0; mf < 4; ++mf) {
    const int col = nt * 64 + wc * 16 + lr;
#pragma unroll
    for (int i = 0; i < 4; ++i) {
      const int lrow = wr * 64 + mf * 16 + lq * 4 + i;
      const int r = ldsRow[lrow];
      if (r < 0) continue;
      obuf[(size_t)r * HDIM + col] = acc[mf][i];
    }
  }
}

// ---------------- combine: out[t] = obuf[2t] + obuf[2t+1] ----------------
__global__ __launch_bounds__(256) void combine_k(const float* __restrict__ obuf,
                                                 float* __restrict__ out)
{
  const int i = blockIdx.x * 256 + threadIdx.x;
  const int t = i >> 8, c = i & 255;
  const float4* o4 = (const float4*)obuf;
  const float4 a = o4[(size_t)(2 * t) * (HDIM / 4) + c];
  const float4 b = o4[(size_t)(2 * t + 1) * (HDIM / 4) + c];
  float4 r; r.x = a.x + b.x; r.y = a.y + b.y; r.z = a.z + b.z; r.w = a.w + b.w;
  ((float4*)out)[i] = r;
}

extern "C" void kernel_launch(void* const* d_in, const int* in_sizes, int n_in,
                              void* d_out, int out_size, void* d_ws, size_t ws_size,
                              hipStream_t stream) {
  const float* x  = (const float*)d_in[0];
  const float* rw = (const float*)d_in[1];
  const float* wg = (const float*)d_in[2];
  const float* wu = (const float*)d_in[3];
  const float* wd = (const float*)d_in[4];
  float* out = (float*)d_out;

  char* ws = (char*)d_ws;
  unsigned short* hbuf = (unsigned short*)ws;                        // 16 MiB
  unsigned short* xb   = (unsigned short*)(ws + (16u << 20));        // 4 MiB
  int*   cnt   = (int*)  (ws + (20u << 20));                         // 256 B
  int*   rows  = (int*)  (ws + (20u << 20) + 256);                   // 64 KiB
  float* wslot = (float*)(ws + (20u << 20) + 256 + 65536);           // 16 KiB
  unsigned short* wg16 = (unsigned short*)(ws + (24ull << 20));      // 32 MiB
  unsigned short* wu16 = (unsigned short*)(ws + (56ull << 20));      // 32 MiB
  unsigned short* wd16 = (unsigned short*)(ws + (88ull << 20));      // 32 MiB
  float* obuf = (float*)(ws + (24ull << 20));   // 16 MiB, reuses wg16 (dead after gateup)

  hipMemsetAsync(cnt, 0, 256, stream);
  router_conv_k<<<256 + 512, 512, 0, stream>>>(x, rw, wslot, rows, cnt, xb, wg, wu, wg16, wu16);
  gemm_gateup_k<<<256 + NEXP * 16 * 16, 512, 0, stream>>>(xb, wg16, wu16, rows, cnt, wslot,
                                                          hbuf, wd, wd16);
  gemm_down_k<<<NEXP * 16 * 16, 512, 0, stream>>>(hbuf, wd16, rows, cnt, obuf);
  combine_k<<<T_TOK * HDIM / 4 / 256, 256, 0, stream>>>(obuf, out);
}

// Round 8
// 287.910 us; speedup vs baseline: 1.1280x; 1.0199x over previous
//
#include <hip/hip_runtime.h>
#include <hip/hip_bf16.h>
#include <cstdint>
#include <cstddef>

#define T_TOK 2048
#define HDIM  1024
#define FDIM  2048
#define NEXP  8
#define BM    128

typedef __attribute__((ext_vector_type(8))) short bf16x8;
typedef __attribute__((ext_vector_type(4))) float f32x4;

__device__ __forceinline__ unsigned short f2b(float f) {
  __hip_bfloat16 h = __float2bfloat16(f);
  return __builtin_bit_cast(unsigned short, h);
}

__device__ __forceinline__ void gload16(const void* g, void* l) {
  __builtin_amdgcn_global_load_lds(
      (const __attribute__((address_space(1))) unsigned int*)g,
      (__attribute__((address_space(3))) unsigned int*)l, 16, 0, 0);
}

__device__ __forceinline__ void cvt8(const float* __restrict__ s,
                                     unsigned short* __restrict__ d, int i) {
  const float4 f0 = ((const float4*)s)[2 * i];
  const float4 f1 = ((const float4*)s)[2 * i + 1];
  union { unsigned short u[8]; uint4 v; } p;
  p.u[0] = f2b(f0.x); p.u[1] = f2b(f0.y); p.u[2] = f2b(f0.z); p.u[3] = f2b(f0.w);
  p.u[4] = f2b(f1.x); p.u[5] = f2b(f1.y); p.u[6] = f2b(f1.z); p.u[7] = f2b(f1.w);
  ((uint4*)d)[i] = p.v;
}

// ---------------- router (512 blocks) + wg/wu conversion (1024 blocks) ----------------
__global__ __launch_bounds__(256) void router_conv_k(
    const float* __restrict__ x, const float* __restrict__ rw,
    float* __restrict__ wslot, int* __restrict__ rows,
    int* __restrict__ cnt, unsigned short* __restrict__ xb,
    const float* __restrict__ wg32, const float* __restrict__ wu32,
    unsigned short* __restrict__ wg16, unsigned short* __restrict__ wu16)
{
  const int bx = blockIdx.x;
  if (bx >= 512) {
    const int b2 = bx - 512;                 // 0..1023
    const float* s = (b2 < 512) ? wg32 : wu32;
    unsigned short* d = (b2 < 512) ? wg16 : wu16;
    const int base = (b2 & 511) * 256 + threadIdx.x;   // 131072 threads/tensor
#pragma unroll
    for (int it = 0; it < 16; ++it) cvt8(s, d, base + it * 131072);
    return;
  }
  const int wave = threadIdx.x >> 6, lane = threadIdx.x & 63;
  const int t = bx * 4 + wave;
  const float* xr = x + (size_t)t * HDIM;
  unsigned short* xbr = xb + (size_t)t * HDIM;
  float acc[NEXP];
#pragma unroll
  for (int e = 0; e < NEXP; ++e) acc[e] = 0.f;
  for (int i = 0; i < HDIM / 64; ++i) {
    const int h = i * 64 + lane;
    const float xv = xr[h];
    xbr[h] = f2b(xv);
#pragma unroll
    for (int e = 0; e < NEXP; ++e) acc[e] += xv * rw[e * HDIM + h];
  }
#pragma unroll
  for (int e = 0; e < NEXP; ++e) {
#pragma unroll
    for (int off = 32; off; off >>= 1) acc[e] += __shfl_xor(acc[e], off);
  }
  if (lane == 0) {
    float m1 = acc[0]; int i1 = 0;
#pragma unroll
    for (int e = 1; e < NEXP; ++e) if (acc[e] > m1) { m1 = acc[e]; i1 = e; }
    float sum1 = 0.f;
#pragma unroll
    for (int e = 0; e < NEXP; ++e) {
      const float f = fmaxf(fabsf(acc[e]), m1);
      if (m1 - acc[e] <= 0.02f * f) sum1 += expf(acc[e] - m1);
    }
    float m2 = -3.4e38f; int i2 = 0;
#pragma unroll
    for (int e = 0; e < NEXP; ++e)
      if (e != i1 && acc[e] > m2) { m2 = acc[e]; i2 = e; }
    float sum2 = 0.f;
#pragma unroll
    for (int e = 0; e < NEXP; ++e) {
      if (e == i1) continue;
      const float f = fmaxf(fabsf(acc[e]), m2);
      if (m2 - acc[e] <= 0.02f * f) sum2 += expf(acc[e] - m2);
    }
    wslot[2 * t]     = 1.f / sum1;
    wslot[2 * t + 1] = 1.f / sum2;
    int p1 = atomicAdd(&cnt[i1], 1); rows[i1 * T_TOK + p1] = 2 * t;
    int p2 = atomicAdd(&cnt[i2], 1); rows[i2 * T_TOK + p2] = 2 * t + 1;
  }
}

// ---------------- gate/up GEMM: 128x64x32, 256 thr, single-buf, frag-major LDS ----
// chunk = 512 bf16 (16 rows x 32 k), lane-linear 16B. A chunks 0..7, B chunks 0..3.
// + 256 leading blocks convert wd (overlapped).
__global__ __launch_bounds__(256) void gemm_gateup_k(
    const unsigned short* __restrict__ xb,
    const unsigned short* __restrict__ wg16, const unsigned short* __restrict__ wu16,
    const int* __restrict__ rows, const int* __restrict__ cnt,
    const float* __restrict__ wslot, unsigned short* __restrict__ hbuf,
    const float* __restrict__ wd32, unsigned short* __restrict__ wd16)
{
  const int bx = blockIdx.x;
  if (bx < 256) {   // leading: wd fp32->bf16, overlaps GEMM blocks
    const int base = bx * 256 + threadIdx.x;
#pragma unroll
    for (int it = 0; it < 32; ++it) cvt8(wd32, wd16, base + it * 65536);
    return;
  }
  const int bxx = bx - 256;
  const int e  = bxx >> 9;          // 16 mt x 32 nt
  const int rm = bxx & 511;
  const int mt = rm >> 5;
  const int nt = rm & 31;
  const int cnt_e = cnt[e];
  if (mt * BM >= cnt_e) return;

  __shared__ unsigned short As[4096];   // 8 chunks x 512
  __shared__ unsigned short Bg[2048];   // 4 chunks x 512
  __shared__ unsigned short Bu[2048];
  __shared__ int ldsRow[BM];

  const int tid = threadIdx.x;
  if (tid < BM) {
    const int idx = mt * BM + tid;
    ldsRow[tid] = (idx < cnt_e) ? rows[e * T_TOK + idx] : -1;
  }
  __syncthreads();

  const int lane = tid & 63, w = tid >> 6;       // 4 waves
  const int wr = w >> 1, wc = w & 1;             // 2x2: wave = 64 rows x 32 cols
  const int lr = lane & 15, lq = lane >> 4;

  // A staging: wave w stages chunks {w, w+4}; chunk c: rows c*16..+16
  const unsigned short* aS[2];
  int aOff[2];
#pragma unroll
  for (int it = 0; it < 2; ++it) {
    const int c = w + 4 * it;
    int r = ldsRow[c * 16 + lr]; if (r < 0) r = 0;
    aS[it] = xb + (size_t)(r >> 1) * HDIM + lq * 8;
    aOff[it] = c * 512 + lane * 8;
  }
  // B staging: wave w stages chunk w of Bg and Bu; chunk c: N-rows c*16..+16
  const unsigned short* gS = wg16 + ((size_t)e * FDIM + nt * 64 + w * 16 + lr) * HDIM + lq * 8;
  const unsigned short* uS = wu16 + ((size_t)e * FDIM + nt * 64 + w * 16 + lr) * HDIM + lq * 8;
  const int bOff = w * 512 + lane * 8;

  f32x4 accg[4][2], accu[4][2];
#pragma unroll
  for (int mf = 0; mf < 4; ++mf)
#pragma unroll
    for (int nf = 0; nf < 2; ++nf) {
      accg[mf][nf] = (f32x4){0.f, 0.f, 0.f, 0.f};
      accu[mf][nf] = (f32x4){0.f, 0.f, 0.f, 0.f};
    }

  for (int k = 0; k < 32; ++k) {        // K = 1024, BK = 32
    const int ko = k * 32;
    gload16(aS[0] + ko, &As[aOff[0]]);
    gload16(aS[1] + ko, &As[aOff[1]]);
    gload16(gS + ko, &Bg[bOff]);
    gload16(uS + ko, &Bu[bOff]);
    __syncthreads();                    // drain: tile staged

    bf16x8 a[4], bg[2], bu[2];
#pragma unroll
    for (int mf = 0; mf < 4; ++mf)
      a[mf] = *(const bf16x8*)&As[(wr * 4 + mf) * 512 + lane * 8];
#pragma unroll
    for (int nf = 0; nf < 2; ++nf) {
      bg[nf] = *(const bf16x8*)&Bg[(wc * 2 + nf) * 512 + lane * 8];
      bu[nf] = *(const bf16x8*)&Bu[(wc * 2 + nf) * 512 + lane * 8];
    }
#pragma unroll
    for (int mf = 0; mf < 4; ++mf)
#pragma unroll
      for (int nf = 0; nf < 2; ++nf) {
        accg[mf][nf] = __builtin_amdgcn_mfma_f32_16x16x32_bf16(a[mf], bg[nf], accg[mf][nf], 0, 0, 0);
        accu[mf][nf] = __builtin_amdgcn_mfma_f32_16x16x32_bf16(a[mf], bu[nf], accu[mf][nf], 0, 0, 0);
      }
    __syncthreads();                    // protect LDS before restage
  }

  // epilogue: h = silu(g)*u*w   (C/D: col=lane&15, row=(lane>>4)*4+i)
#pragma unroll
  for (int mf = 0; mf < 4; ++mf)
#pragma unroll
    for (int nf = 0; nf < 2; ++nf) {
      const int col = nt * 64 + wc * 32 + nf * 16 + lr;
#pragma unroll
      for (int i = 0; i < 4; ++i) {
        const int lrow = wr * 64 + mf * 16 + lq * 4 + i;
        const int r = ldsRow[lrow];
        if (r < 0) continue;
        const float g = accg[mf][nf][i], u = accu[mf][nf][i];
        const float val = g / (1.f + __expf(-g)) * u * wslot[r];
        hbuf[(size_t)r * FDIM + col] = f2b(val);
      }
    }
}

// ---------------- down GEMM: 128x64x64, 256 thr, single-buf, frag-major LDS ----
// A: 16 chunks (c: row-block c>>1, k-half c&1); B: 8 chunks (col-block c>>1, k-half c&1).
__global__ __launch_bounds__(256) void gemm_down_k(
    const unsigned short* __restrict__ hbuf,
    const unsigned short* __restrict__ wd16,
    const int* __restrict__ rows, const int* __restrict__ cnt,
    float* __restrict__ obuf)
{
  const int bx = blockIdx.x;
  const int e  = bx >> 8;           // 16 mt x 16 nt
  const int mt = (bx >> 4) & 15;
  const int nt = bx & 15;
  const int cnt_e = cnt[e];
  if (mt * BM >= cnt_e) return;

  __shared__ unsigned short As[8192];   // 16 chunks x 512
  __shared__ unsigned short Bs[4096];   // 8 chunks x 512
  __shared__ int ldsRow[BM];

  const int tid = threadIdx.x;
  if (tid < BM) {
    const int idx = mt * BM + tid;
    ldsRow[tid] = (idx < cnt_e) ? rows[e * T_TOK + idx] : -1;
  }
  __syncthreads();

  const int lane = tid & 63, w = tid >> 6;
  const int wr = w >> 1, wc = w & 1;    // 2x2: wave = 64 rows x 32 cols
  const int lr = lane & 15, lq = lane >> 4;
  const int kh = (w & 1) * 32;          // this wave's k-half within BK=64
  const int rb0 = w >> 1;

  // A staging: wave w stages chunks c = w+4*it (it 0..3): row-block (rb0+2it), k-half w&1
  const unsigned short* aS[4];
  int aOff[4];
#pragma unroll
  for (int it = 0; it < 4; ++it) {
    const int c = w + 4 * it;
    int r = ldsRow[(rb0 + 2 * it) * 16 + lr]; if (r < 0) r = 0;
    aS[it] = hbuf + (size_t)r * FDIM + kh + lq * 8;
    aOff[it] = c * 512 + lane * 8;
  }
  // B staging: wave w stages chunks c = w+4*j (j 0..1): col-block (rb0+2j), k-half w&1
  const unsigned short* bS[2];
  int bOff[2];
#pragma unroll
  for (int j = 0; j < 2; ++j) {
    const int c = w + 4 * j;
    bS[j] = wd16 + ((size_t)e * HDIM + nt * 64 + (rb0 + 2 * j) * 16 + lr) * FDIM + kh + lq * 8;
    bOff[j] = c * 512 + lane * 8;
  }

  f32x4 acc[4][2];
#pragma unroll
  for (int mf = 0; mf < 4; ++mf)
#pragma unroll
    for (int nf = 0; nf < 2; ++nf) acc[mf][nf] = (f32x4){0.f, 0.f, 0.f, 0.f};

  for (int k = 0; k < 32; ++k) {        // K = 2048, BK = 64
    const int ko = k * 64;
    gload16(aS[0] + ko, &As[aOff[0]]);
    gload16(aS[1] + ko, &As[aOff[1]]);
    gload16(aS[2] + ko, &As[aOff[2]]);
    gload16(aS[3] + ko, &As[aOff[3]]);
    gload16(bS[0] + ko, &Bs[bOff[0]]);
    gload16(bS[1] + ko, &Bs[bOff[1]]);
    __syncthreads();

    bf16x8 a[4][2], b[2][2];
#pragma unroll
    for (int mf = 0; mf < 4; ++mf)
#pragma unroll
      for (int ks = 0; ks < 2; ++ks)
        a[mf][ks] = *(const bf16x8*)&As[((wr * 4 + mf) * 2 + ks) * 512 + lane * 8];
#pragma unroll
    for (int nf = 0; nf < 2; ++nf)
#pragma unroll
      for (int ks = 0; ks < 2; ++ks)
        b[nf][ks] = *(const bf16x8*)&Bs[((wc * 2 + nf) * 2 + ks) * 512 + lane * 8];
#pragma unroll
    for (int mf = 0; mf < 4; ++mf)
#pragma unroll
      for (int nf = 0; nf < 2; ++nf)
#pragma unroll
        for (int ks = 0; ks < 2; ++ks)
          acc[mf][nf] = __builtin_amdgcn_mfma_f32_16x16x32_bf16(a[mf][ks], b[nf][ks], acc[mf][nf], 0, 0, 0);
    __syncthreads();
  }

#pragma unroll
  for (int mf = 0; mf < 4; ++mf)
#pragma unroll
    for (int nf = 0; nf < 2; ++nf) {
      const int col = nt * 64 + wc * 32 + nf * 16 + lr;
#pragma unroll
      for (int i = 0; i < 4; ++i) {
        const int lrow = wr * 64 + mf * 16 + lq * 4 + i;
        const int r = ldsRow[lrow];
        if (r < 0) continue;
        obuf[(size_t)r * HDIM + col] = acc[mf][nf][i];
      }
    }
}

// ---------------- combine: out[t] = obuf[2t] + obuf[2t+1] ----------------
__global__ __launch_bounds__(256) void combine_k(const float* __restrict__ obuf,
                                                 float* __restrict__ out)
{
  const int i = blockIdx.x * 256 + threadIdx.x;
  const int t = i >> 8, c = i & 255;
  const float4* o4 = (const float4*)obuf;
  const float4 a = o4[(size_t)(2 * t) * (HDIM / 4) + c];
  const float4 b = o4[(size_t)(2 * t + 1) * (HDIM / 4) + c];
  float4 r; r.x = a.x + b.x; r.y = a.y + b.y; r.z = a.z + b.z; r.w = a.w + b.w;
  ((float4*)out)[i] = r;
}

extern "C" void kernel_launch(void* const* d_in, const int* in_sizes, int n_in,
                              void* d_out, int out_size, void* d_ws, size_t ws_size,
                              hipStream_t stream) {
  const float* x  = (const float*)d_in[0];
  const float* rw = (const float*)d_in[1];
  const float* wg = (const float*)d_in[2];
  const float* wu = (const float*)d_in[3];
  const float* wd = (const float*)d_in[4];
  float* out = (float*)d_out;

  char* ws = (char*)d_ws;
  unsigned short* hbuf = (unsigned short*)ws;                        // 16 MiB
  unsigned short* xb   = (unsigned short*)(ws + (16u << 20));        // 4 MiB
  int*   cnt   = (int*)  (ws + (20u << 20));                         // 256 B
  int*   rows  = (int*)  (ws + (20u << 20) + 256);                   // 64 KiB
  float* wslot = (float*)(ws + (20u << 20) + 256 + 65536);           // 16 KiB
  unsigned short* wg16 = (unsigned short*)(ws + (24ull << 20));      // 32 MiB
  unsigned short* wu16 = (unsigned short*)(ws + (56ull << 20));      // 32 MiB
  unsigned short* wd16 = (unsigned short*)(ws + (88ull << 20));      // 32 MiB
  float* obuf = (float*)(ws + (24ull << 20));   // 16 MiB, reuses wg16 (dead after gateup)

  hipMemsetAsync(cnt, 0, 256, stream);
  router_conv_k<<<512 + 1024, 256, 0, stream>>>(x, rw, wslot, rows, cnt, xb, wg, wu, wg16, wu16);
  gemm_gateup_k<<<256 + NEXP * 16 * 32, 256, 0, stream>>>(xb, wg16, wu16, rows, cnt, wslot,
                                                          hbuf, wd, wd16);
  gemm_down_k<<<NEXP * 16 * 16, 256, 0, stream>>>(hbuf, wd16, rows, cnt, obuf);
  combine_k<<<T_TOK * HDIM / 4 / 256, 256, 0, stream>>>(obuf, out);
}